// Round 23
// baseline (601.525 us; speedup 1.0000x reference)
//
#include <hip/hip_runtime.h>
#include <hip/hip_bf16.h>
#include <stdint.h>

typedef __hip_bfloat16 bf16;
typedef __attribute__((ext_vector_type(8))) short bf16x8;
typedef __attribute__((ext_vector_type(8))) short short8;
typedef __attribute__((ext_vector_type(4))) float f32x4;

#define DEV __device__ __forceinline__

static constexpr int Bn = 16, Tn = 512, En = 512, Hn = 8, Ln = 4, Vn = 2048;
static constexpr int HSn = 64, FFn = 2048, Mn = Bn * Tn;  // M = 8192
static constexpr int SQ = 1536;                           // fused qkv row stride

DEV f32x4 mfma16(bf16x8 a, bf16x8 b, f32x4 c) {
  return __builtin_amdgcn_mfma_f32_16x16x32_bf16(a, b, c, 0, 0, 0);
}
DEV float b2f(bf16 x) { return __bfloat162float(x); }
DEV bf16 f2b(float x) { return __float2bfloat16(x); }
DEV short f2s(float x) { bf16 h = f2b(x); return reinterpret_cast<short&>(h); }
DEV float s2f(short x) { return __bfloat162float(reinterpret_cast<bf16&>(x)); }

// async global->LDS, 16B per lane; LDS dest = base + lane*16 (wave-uniform base).
DEV void gload16(const void* g, void* l) {
  __builtin_amdgcn_global_load_lds(
      (const __attribute__((address_space(1))) void*)(uintptr_t)g,
      (__attribute__((address_space(3))) void*)(uint32_t)(uintptr_t)l, 16, 0, 0);
}

// ------------- merged prep: weight transposes + rel cast + embedding -------------
// blocks [0,13312): transpose+cast tiles; [13312,14335): rel cast; [14335,16383): embed.
__global__ __launch_bounds__(256) void kprep(
    const float* __restrict__ Wq, const float* __restrict__ Wk,
    const float* __restrict__ Wv, const float* __restrict__ Wo,
    const float* __restrict__ W1, const float* __restrict__ W2,
    const float* __restrict__ Wlm, const float* __restrict__ rel,
    const int* __restrict__ idx, const float* __restrict__ tok,
    const float* __restrict__ pos,
    bf16* __restrict__ wqkvT, bf16* __restrict__ woT, bf16* __restrict__ w1T,
    bf16* __restrict__ w2T, bf16* __restrict__ wlmT, bf16* __restrict__ relc,
    bf16* __restrict__ x) {
  int id = blockIdx.x;
  if (id < 13312) {
    const float* in;
    bf16* out;
    int R, C, z, cx, cy;
    long in_zs, out_zs;
    if (id < 3072) {  // Wq|Wk|Wv -> wqkvT (out row-stride via out_zs=SQ*En per layer)
      int part = id >> 10, inner = id & 1023;
      z = inner >> 8;
      int tile = inner & 255;
      cx = tile & 15; cy = tile >> 4;
      in = part == 0 ? Wq : (part == 1 ? Wk : Wv);
      out = wqkvT + part * 512 * 512;
      R = En; C = En; in_zs = (long)En * En; out_zs = (long)SQ * En;
    } else if (id < 4096) {
      int inner = id - 3072;
      z = inner >> 8;
      int tile = inner & 255;
      cx = tile & 15; cy = tile >> 4;
      in = Wo; out = woT; R = En; C = En;
      in_zs = (long)En * En; out_zs = (long)En * En;
    } else if (id < 8192) {
      int inner = id - 4096;
      z = inner >> 10;
      int tile = inner & 1023;
      cx = tile & 63; cy = tile >> 6;
      in = W1; out = w1T; R = En; C = FFn;
      in_zs = (long)En * FFn; out_zs = (long)En * FFn;
    } else if (id < 12288) {
      int inner = id - 8192;
      z = inner >> 10;
      int tile = inner & 1023;
      cx = tile & 15; cy = tile >> 4;
      in = W2; out = w2T; R = FFn; C = En;
      in_zs = (long)FFn * En; out_zs = (long)FFn * En;
    } else {
      int tile = id - 12288;
      z = 0;
      cx = tile & 63; cy = tile >> 6;
      in = Wlm; out = wlmT; R = En; C = Vn;
      in_zs = 0; out_zs = 0;
    }
    __shared__ float tile_s[32][33];
    int tx = threadIdx.x & 31, ty = threadIdx.x >> 5;
    const float* inz = in + (size_t)z * in_zs;
    bf16* outz = out + (size_t)z * out_zs;
    int c0 = cx * 32, r0 = cy * 32;
    for (int k = 0; k < 32; k += 8)
      tile_s[ty + k][tx] = inz[(size_t)(r0 + ty + k) * C + (c0 + tx)];
    __syncthreads();
    for (int k = 0; k < 32; k += 8)
      outz[(size_t)(c0 + ty + k) * R + (r0 + tx)] = f2b(tile_s[tx][ty + k]);
  } else if (id < 14335) {
    int i = (id - 13312) * 256 + threadIdx.x;  // exactly covers 261888
    relc[i] = f2b(rel[i]);
  } else {
    int i = (id - 14335) * 256 + threadIdx.x;  // over M*E/8
    int e8 = (i & 63) * 8;
    int bt = i >> 6;
    int t = bt & (Tn - 1);
    const float* tp = tok + (size_t)idx[bt] * En + e8;
    const float* pp = pos + (size_t)t * En + e8;
    f32x4 t0 = *(const f32x4*)tp, t1 = *(const f32x4*)(tp + 4);
    f32x4 p0 = *(const f32x4*)pp, p1 = *(const f32x4*)(pp + 4);
    short8 ov;
    for (int j = 0; j < 4; j++) {
      ov[j] = f2s(t0[j] + p0[j]);
      ov[j + 4] = f2s(t1[j] + p1[j]);
    }
    *(short8*)(x + (size_t)bt * En + e8) = ov;
  }
}

// ------------- LayerNorm (bf16 x): 4 rows/block, wave per row -------------
__global__ __launch_bounds__(256) void kln(const bf16* __restrict__ x,
                                           const float* __restrict__ g,
                                           const float* __restrict__ b,
                                           bf16* __restrict__ out) {
  int row = blockIdx.x * 4 + (threadIdx.x >> 6);
  int lane = threadIdx.x & 63;
  short8 xv = *(const short8*)(x + (size_t)row * En + lane * 8);
  float v[8], s = 0.f;
  for (int j = 0; j < 8; j++) { v[j] = s2f(xv[j]); s += v[j]; }
  for (int m = 1; m < 64; m <<= 1) s += __shfl_xor(s, m);
  float mean = s * (1.f / En);
  float s2 = 0.f;
  for (int j = 0; j < 8; j++) { float d = v[j] - mean; s2 += d * d; }
  for (int m = 1; m < 64; m <<= 1) s2 += __shfl_xor(s2, m);
  float rstd = rsqrtf(s2 * (1.f / En) + 1e-5f);
  f32x4 g0 = *(const f32x4*)(g + lane * 8), g1 = *(const f32x4*)(g + lane * 8 + 4);
  f32x4 b0 = *(const f32x4*)(b + lane * 8), b1 = *(const f32x4*)(b + lane * 8 + 4);
  short8 ov;
  for (int j = 0; j < 4; j++) {
    ov[j] = f2s((v[j] - mean) * rstd * g0[j] + b0[j]);
    ov[j + 4] = f2s((v[j + 4] - mean) * rstd * g1[j] + b1[j]);
  }
  *(short8*)(out + (size_t)row * En + lane * 8) = ov;
}

// ------------- GEMM (2-phase): C = A[M,K] @ Bt[N,K]^T, BMxBN, BK=64 ------
// MODE: 0 bf16 store outh; 1 bf16 residual += outh; 2 fp32 store outf.
template <int BM, int BN, int TW, int DB, int SWZ, int NBIAS, int RELU, int MODE>
__global__ __launch_bounds__(TW) void kgemm(const bf16* __restrict__ A,
                                            const bf16* __restrict__ Bt,
                                            const float* __restrict__ bias,
                                            float* __restrict__ outf,
                                            bf16* __restrict__ outh, int Ndim, int K) {
  constexpr int NW = TW / 64;
  constexpr int WCN = NW / 2;
  constexpr int WM = BM / 2, WN = BN / WCN, MI = WM / 16, NI = WN / 16;
  constexpr int NB = DB ? 2 : 1;
  __shared__ bf16 As[NB][BM * 64];
  __shared__ bf16 Bs[NB][BN * 64];
  int t = threadIdx.x, lane = t & 63, w = t >> 6;
  int lr = lane & 15, lg = lane >> 4;
  int sx = lr & 7;
  int wr = w / WCN, wc = w % WCN;
  int bx, by;
  if (SWZ) {
    int id = blockIdx.x + gridDim.x * blockIdx.y;
    int xcd = id & 7, s = id >> 3;
    int gx = gridDim.x;
    by = xcd * 8 + s / gx;
    bx = s % gx;
  } else {
    bx = blockIdx.x; by = blockIdx.y;
  }
  int br = by * BM, bc = bx * BN;
  f32x4 acc[MI][NI] = {};
  int rl = lane >> 3, cb = (lane & 7) ^ rl;
  const bf16* Abase = A + (size_t)(br + w * (BM / NW) + rl) * K + cb * 8;
  const bf16* Bbase = Bt + (size_t)(bc + w * (BN / NW) + rl) * K + cb * 8;

  auto STAGE = [&](int buf, int kt) {
    for (int c = 0; c < BM / (8 * NW); c++)
      gload16(Abase + (size_t)(c * 8) * K + kt, &As[buf][(w * (BM / NW) + c * 8) * 64]);
    for (int c = 0; c < BN / (8 * NW); c++)
      gload16(Bbase + (size_t)(c * 8) * K + kt, &Bs[buf][(w * (BN / NW) + c * 8) * 64]);
  };
  auto COMPUTE = [&](int buf) {
    for (int kk = 0; kk < 2; kk++) {
      int gb = (kk * 4 + lg) ^ sx;
      bf16x8 af[MI], bfr[NI];
      for (int mi = 0; mi < MI; mi++)
        af[mi] = *(const bf16x8*)&As[buf][(wr * WM + mi * 16 + lr) * 64 + gb * 8];
      for (int ni = 0; ni < NI; ni++)
        bfr[ni] = *(const bf16x8*)&Bs[buf][(wc * WN + ni * 16 + lr) * 64 + gb * 8];
      for (int mi = 0; mi < MI; mi++)
        for (int ni = 0; ni < NI; ni++)
          acc[mi][ni] = mfma16(af[mi], bfr[ni], acc[mi][ni]);
    }
  };

  if (DB) {
    STAGE(0, 0);
    __syncthreads();
    int nt = K / 64;
    for (int t2 = 0; t2 < nt; t2++) {
      int cur = t2 & 1;
      if (t2 + 1 < nt) STAGE(cur ^ 1, (t2 + 1) * 64);
      COMPUTE(cur);
      __syncthreads();
    }
  } else {
    for (int kt = 0; kt < K; kt += 64) {
      __syncthreads();
      STAGE(0, kt);
      __syncthreads();
      COMPUTE(0);
    }
  }

  for (int mi = 0; mi < MI; mi++)
    for (int ni = 0; ni < NI; ni++)
      for (int r = 0; r < 4; r++) {
        int row = br + wr * WM + mi * 16 + lg * 4 + r;
        int col = bc + wc * WN + ni * 16 + lr;
        float val = acc[mi][ni][r];
        if (NBIAS) val += bias[col];
        if (RELU) val = fmaxf(val, 0.f);
        if (MODE == 1) {
          bf16* p = outh + (size_t)row * Ndim + col;
          *p = f2b(b2f(*p) + val);
        } else if (MODE == 2) {
          outf[(size_t)row * Ndim + col] = val;
        } else {
          outh[(size_t)row * Ndim + col] = f2b(val);
        }
      }
}

// ------------- GEMM (8-phase counted-vmcnt): 256x256, BK=64, 512 thr ------
// Grid (GX, 32), N = GX*256, GX*32 % 8 == 0. Generalized bijective XCD swizzle:
// lin = xcd*(GX*4) + (id>>3); by = lin/GX; bx = lin%GX  (== proven map at GX=8).
// Raw asm barriers; counted vmcnt. MODE: 0 bf16 store; 2 fp32 store. K/64 >= 2.
template <int GX, int NBIAS, int RELU, int MODE>
__global__ __launch_bounds__(512) void kgemm8(const bf16* __restrict__ A,
                                              const bf16* __restrict__ Bt,
                                              const float* __restrict__ bias,
                                              float* __restrict__ outf,
                                              bf16* __restrict__ outh, int Ndim, int K) {
  __shared__ bf16 As[2][256 * 64];
  __shared__ bf16 Bs[2][256 * 64];
  int t = threadIdx.x, lane = t & 63, w = t >> 6;
  int lr = lane & 15, lg = lane >> 4;
  int sx = lr & 7;
  int wr = w >> 2, wc = w & 3;
  int rl8 = lane >> 3, cb = (lane & 7) ^ rl8;
  int id = blockIdx.x + GX * blockIdx.y;         // grid (GX, 32)
  int xcd = id & 7, s = id >> 3;
  int lin = xcd * (GX * 4) + s;
  int by = lin / GX, bx = lin % GX;              // bijective XCD panel swizzle
  int br = by * 256, bc = bx * 256;
  f32x4 acc[8][4] = {};
  const bf16* Abase = A + (size_t)(br + w * 16 + rl8) * K + cb * 8;
  const bf16* Bbase = Bt + (size_t)(bc + w * 16 + rl8) * K + cb * 8;

  auto STAGEH = [&](int hh, int buf, int kt) {
    int half = hh & 1;
    if (hh < 2) {
      const bf16* g = Abase + (size_t)(half * 128) * K + kt;
      bf16* l = &As[buf][(half * 128 + w * 16) * 64];
      gload16(g, l);
      gload16(g + (size_t)8 * K, l + 8 * 64);
    } else {
      const bf16* g = Bbase + (size_t)(half * 128) * K + kt;
      bf16* l = &Bs[buf][(half * 128 + w * 16) * 64];
      gload16(g, l);
      gload16(g + (size_t)8 * K, l + 8 * 64);
    }
  };

#define PHASE8(Q, P)                                                          \
  do {                                                                        \
    constexpr int mh = (Q) >> 1, nh = (Q) & 1;                                \
    bf16x8 af[4][2], bfr[2][2];                                               \
    _Pragma("unroll") for (int kk = 0; kk < 2; kk++) {                        \
      int gb = (kk * 4 + lg) ^ sx;                                            \
      _Pragma("unroll") for (int i = 0; i < 4; i++)                           \
        af[i][kk] = *(const bf16x8*)&As[P][(wr * 128 + (mh * 4 + i) * 16 + lr) * 64 + gb * 8]; \
      _Pragma("unroll") for (int j = 0; j < 2; j++)                           \
        bfr[j][kk] = *(const bf16x8*)&Bs[P][(wc * 64 + (nh * 2 + j) * 16 + lr) * 64 + gb * 8]; \
    }                                                                         \
    __builtin_amdgcn_s_setprio(1);                                            \
    _Pragma("unroll") for (int i = 0; i < 4; i++)                             \
      _Pragma("unroll") for (int j = 0; j < 2; j++) {                         \
        acc[mh * 4 + i][nh * 2 + j] =                                         \
            mfma16(af[i][0], bfr[j][0], acc[mh * 4 + i][nh * 2 + j]);         \
        acc[mh * 4 + i][nh * 2 + j] =                                         \
            mfma16(af[i][1], bfr[j][1], acc[mh * 4 + i][nh * 2 + j]);         \
      }                                                                       \
    __builtin_amdgcn_s_setprio(0);                                            \
  } while (0)

  int nt = K / 64;  // >= 2 required
  for (int hh = 0; hh < 4; hh++) STAGEH(hh, 0, 0);
  STAGEH(0, 1, 64);
  STAGEH(1, 1, 64);
  asm volatile("s_waitcnt vmcnt(4)" ::: "memory");
  asm volatile("s_barrier" ::: "memory");
  for (int t2 = 0; t2 < nt; t2++) {
    int p = t2 & 1;
    if (t2 + 1 < nt) STAGEH(2, p ^ 1, (t2 + 1) * 64);
    PHASE8(0, p);
    if (t2 + 1 < nt) STAGEH(3, p ^ 1, (t2 + 1) * 64);
    PHASE8(1, p);
    PHASE8(2, p);
    PHASE8(3, p);
    asm volatile("s_barrier" ::: "memory");
    if (t2 + 2 < nt) {
      STAGEH(0, p, (t2 + 2) * 64);
      STAGEH(1, p, (t2 + 2) * 64);
      asm volatile("s_waitcnt vmcnt(4)" ::: "memory");
      asm volatile("s_barrier" ::: "memory");
    } else if (t2 + 1 < nt) {
      asm volatile("s_waitcnt vmcnt(0)" ::: "memory");
      asm volatile("s_barrier" ::: "memory");
    }
  }
#undef PHASE8
#pragma unroll
  for (int mi = 0; mi < 8; mi++)
#pragma unroll
    for (int ni = 0; ni < 4; ni++)
#pragma unroll
      for (int r = 0; r < 4; r++) {
        int row = br + wr * 128 + mi * 16 + lg * 4 + r;
        int col = bc + wc * 64 + ni * 16 + lr;
        float val = acc[mi][ni][r];
        if (NBIAS) val += bias[col];
        if (RELU) val = fmaxf(val, 0.f);
        if (MODE == 2) outf[(size_t)row * Ndim + col] = val;
        else outh[(size_t)row * Ndim + col] = f2b(val);
      }
}

// ------------- fused causal attention, 8-wave paired i-blocks (R14/R16-proven) ------
__global__ __launch_bounds__(512) void kattn(const bf16* __restrict__ qkv,
                                             const bf16* __restrict__ rel,
                                             bf16* __restrict__ ctx) {
  __shared__ bf16 Ks[128 * 64];       // [j][d], col-block XOR (j&7)
  __shared__ bf16 Vs[64 * 128];       // [d][j], col-block (j>>3) XOR (d&7)
  __shared__ bf16 Prel[8][16 * 81];   // per-wave rel panel [ii][m], stride 81
  __shared__ bf16 Ps[8][16 * 64];     // per-wave P [i][j]
  int pairp = blockIdx.x, bh = blockIdx.y;
  int b = bh >> 3, hh = bh & 7;
  int t = threadIdx.x, lane = t & 63, w = t >> 6;   // w in [0,8)
  int wl = w & 3, wg = w >> 2;                      // quarter, group
  int lr = lane & 15, lg = lane >> 4;
  int sx = lr & 7;
  int rl8 = lane >> 3, cbk = (lane & 7) ^ rl8;
  const size_t headrow = (size_t)(b * Tn + hh * 64);
  bf16* prw = &Prel[w][0];
  bf16* psw = &Ps[w][0];
  int jp = t >> 3, db = (t & 7) * 8;  // V staging: rows jp*2, jp*2+1

  int ia = pairp, ib = 7 - pairp;
  int myblk = wg ? ia : ib;
  int mylast = myblk * 64;
  int i0w = myblk * 64 + wl * 16;
  bf16x8 aq[2];
  {
    int t2 = i0w + lr;
    const bf16* qp = qkv + (headrow + (t2 >> 3)) * SQ + (t2 & 7) * 64;
    aq[0] = *(const bf16x8*)(qp + lg * 8);
    aq[1] = *(const bf16x8*)(qp + 32 + lg * 8);
  }
  f32x4 o[4] = {};
  float m_run = -3e38f, l_run = 0.f;
  int ntiles = (ib >> 1) + 1;

  auto SUBTILE = [&](int jb, bool diag, int su) {
    int njmax = diag ? wl : 3;
    int nmmin = diag ? 3 - wl : 0;
    __builtin_amdgcn_s_setprio(1);
    f32x4 sqk[4] = {};
    for (int nj = 0; nj <= njmax; nj++) {
      int row = su * 64 + nj * 16 + lr;
      bf16x8 kb0 = *(const bf16x8*)&Ks[row * 64 + ((lg ^ sx) * 8)];
      bf16x8 kb1 = *(const bf16x8*)&Ks[row * 64 + (((4 + lg) ^ sx) * 8)];
      sqk[nj] = mfma16(kb0, aq[0], sqk[nj]);
      sqk[nj] = mfma16(kb1, aq[1], sqk[nj]);
    }
    int base = i0w - jb + 448;
    for (int nm = nmmin; nm < 5; nm++) {
      int mrow = base + nm * 16 + lr;
      if (mrow > 1022) mrow = 1022;
      const bf16* rp = rel + (size_t)mrow * 64;
      f32x4 sr = {};
      sr = mfma16(aq[0], *(const bf16x8*)(rp + lg * 8), sr);
      sr = mfma16(aq[1], *(const bf16x8*)(rp + 32 + lg * 8), sr);
      for (int r = 0; r < 4; r++)
        prw[(lg * 4 + r) * 81 + nm * 16 + lr] = f2b(sr[r]);
    }
    __builtin_amdgcn_s_setprio(0);
    float sv[4][4];
    for (int nj = 0; nj < 4; nj++)
      for (int r = 0; r < 4; r++) sv[nj][r] = -3e38f;
    float mloc = -3e38f;
    for (int nj = 0; nj <= njmax; nj++)
      for (int r = 0; r < 4; r++) {
        int jj = nj * 16 + lg * 4 + r;
        float val = sqk[nj][r] * 0.125f + b2f(prw[lr * 81 + (lr - jj + 63)]);
        if (jb + jj > i0w + lr) val = -3e38f;
        sv[nj][r] = val;
        mloc = fmaxf(mloc, val);
      }
    mloc = fmaxf(mloc, __shfl_xor(mloc, 16));
    mloc = fmaxf(mloc, __shfl_xor(mloc, 32));
    float mnew = fmaxf(m_run, mloc);
    float corr = __expf(m_run - mnew);
    m_run = mnew;
    float lsum = 0.f;
    for (int nj = 0; nj < 4; nj++)
      for (int r = 0; r < 4; r++) {
        float p = __expf(sv[nj][r] - mnew);
        lsum += p;
        psw[lr * 64 + (((nj * 2 + (lg >> 1)) ^ sx) * 8) + (lg & 1) * 4 + r] = f2b(p);
      }
    lsum += __shfl_xor(lsum, 16);
    lsum += __shfl_xor(lsum, 32);
    l_run = l_run * corr + lsum;
    for (int r = 0; r < 4; r++) {
      float c = __shfl(corr, lg * 4 + r);
      for (int nd = 0; nd < 4; nd++) o[nd][r] *= c;
    }
    __builtin_amdgcn_s_setprio(1);
    bf16x8 ap0 = *(const bf16x8*)&psw[lr * 64 + ((lg ^ sx) * 8)];
    bf16x8 ap1 = *(const bf16x8*)&psw[lr * 64 + (((4 + lg) ^ sx) * 8)];
    for (int nd = 0; nd < 4; nd++) {
      int d = nd * 16 + lr;
      bf16x8 vb0 = *(const bf16x8*)&Vs[d * 128 + ((su * 8 + (lg ^ sx)) * 8)];
      bf16x8 vb1 = *(const bf16x8*)&Vs[d * 128 + ((su * 8 + ((4 + lg) ^ sx)) * 8)];
      o[nd] = mfma16(ap0, vb0, o[nd]);
      o[nd] = mfma16(ap1, vb1, o[nd]);
    }
    __builtin_amdgcn_s_setprio(0);
  };

  for (int jt = 0; jt < ntiles; jt++) {
    int jbase = jt * 128;
    bf16x8 vv[2];
#pragma unroll
    for (int u = 0; u < 2; u++) {
      int j0 = jbase + jp * 2 + u;
      vv[u] = *(const bf16x8*)(qkv + (headrow + (j0 >> 3)) * SQ + (j0 & 7) * 64 + 1024 + db);
    }
    __syncthreads();  // previous-iter readers done
#pragma unroll
    for (int c = 0; c < 2; c++) {
      int row = w * 16 + c * 8 + rl8;
      const bf16* src = qkv + (headrow + ((jbase + row) >> 3)) * SQ +
                        (row & 7) * 64 + 512 + cbk * 8;
      gload16(src, &Ks[(w * 16 + c * 8) * 64]);
    }
    // V transpose into LDS: one paired-b32 store set per thread
    {
      const short* pa = (const short*)&vv[0];
      const short* pb = (const short*)&vv[1];
      int j0 = jp * 2;
      int jblk = j0 >> 3, jin = j0 & 7;
#pragma unroll
      for (int u = 0; u < 8; u++) {
        int d = db + u;
        int idx = d * 128 + ((jblk ^ (d & 7)) * 8) + jin;
        uint32_t pk = (uint32_t)(uint16_t)pa[u] | ((uint32_t)(uint16_t)pb[u] << 16);
        *(uint32_t*)((short*)Vs + idx) = pk;
      }
    }
    __syncthreads();
#pragma unroll
    for (int su = 0; su < 2; su++) {
      int jb = jbase + su * 64;
      if (jb > ib * 64) break;                  // block-uniform
      if (jb <= mylast) SUBTILE(jb, jb == mylast, su);
    }
  }  // jt
  for (int r = 0; r < 4; r++) {
    float linv = 1.f / __shfl(l_run, lg * 4 + r);
    int row = i0w + lg * 4 + r;
    for (int nd = 0; nd < 4; nd++)
      ctx[((size_t)b * Tn + row) * En + hh * 64 + nd * 16 + lr] = f2b(o[nd][r] * linv);
  }
}

// ------------- launch -------------
extern "C" void kernel_launch(void* const* d_in, const int* in_sizes, int n_in,
                              void* d_out, int out_size, void* d_ws, size_t ws_size,
                              hipStream_t stream) {
  (void)in_sizes; (void)n_in; (void)out_size; (void)ws_size;
  const int* idx = (const int*)d_in[0];
  const float* tok = (const float*)d_in[1];
  const float* pos = (const float*)d_in[2];
  const float* Wq = (const float*)d_in[3];
  const float* Wk = (const float*)d_in[4];
  const float* Wv = (const float*)d_in[5];
  const float* rel = (const float*)d_in[6];
  const float* Wo = (const float*)d_in[7];
  const float* bo = (const float*)d_in[8];
  const float* ln1_g = (const float*)d_in[9];
  const float* ln1_b = (const float*)d_in[10];
  const float* W1 = (const float*)d_in[11];
  const float* b1 = (const float*)d_in[12];
  const float* W2 = (const float*)d_in[13];
  const float* b2 = (const float*)d_in[14];
  const float* ln2_g = (const float*)d_in[15];
  const float* ln2_b = (const float*)d_in[16];
  const float* lnf_g = (const float*)d_in[17];
  const float* lnf_b = (const float*)d_in[18];
  const float* Wlm = (const float*)d_in[19];
  const float* blm = (const float*)d_in[20];

  char* ws = (char*)d_ws;
  bf16* x = (bf16*)(ws + 0);                 // 8 MB bf16 residual
  bf16* h = (bf16*)(ws + 16777216);          // 8 MB LN out
  bf16* qkv = (bf16*)(ws + 25165824);        // 24 MB fused q|k|v [M][1536]
  bf16* ctx = (bf16*)(ws + 50331648);        // 8 MB
  bf16* ffn1 = qkv;                          // 32 MB alias over qkv+ctx
  bf16* wqkvT = (bf16*)(ws + 58720256);      // [L][1536][512]
  bf16* woT = wqkvT + (size_t)Ln * SQ * En;
  bf16* w1T = woT + (size_t)Ln * En * En;
  bf16* w2T = w1T + (size_t)Ln * En * FFn;
  bf16* wlmT = w2T + (size_t)Ln * FFn * En;
  bf16* relc = wlmT + (size_t)En * Vn;
  float* outf = (float*)d_out;

  kprep<<<16383, 256, 0, stream>>>(Wq, Wk, Wv, Wo, W1, W2, Wlm, rel, idx, tok, pos,
                                   wqkvT, woT, w1T, w2T, wlmT, relc, x);

  for (int l = 0; l < Ln; l++) {
    kln<<<Mn / 4, 256, 0, stream>>>(x, ln1_g + (size_t)l * En, ln1_b + (size_t)l * En, h);
    kgemm8<6, 0, 0, 0><<<dim3(6, 32), 512, 0, stream>>>(
        h, wqkvT + (size_t)l * SQ * En, nullptr, nullptr, qkv, SQ, En);
    kattn<<<dim3(4, 128), 512, 0, stream>>>(
        qkv, relc + (size_t)l * (2 * Tn - 1) * HSn, ctx);
    kgemm<128, 128, 512, 1, 1, 1, 0, 1><<<dim3(4, 64), 512, 0, stream>>>(
        ctx, woT + (size_t)l * En * En, bo + (size_t)l * En, nullptr, x, En, En);
    kln<<<Mn / 4, 256, 0, stream>>>(x, ln2_g + (size_t)l * En, ln2_b + (size_t)l * En, h);
    kgemm8<8, 1, 1, 0><<<dim3(8, 32), 512, 0, stream>>>(
        h, w1T + (size_t)l * En * FFn, b1 + (size_t)l * FFn, nullptr, ffn1, FFn, En);
    kgemm<128, 128, 512, 1, 1, 1, 0, 1><<<dim3(4, 64), 512, 0, stream>>>(
        ffn1, w2T + (size_t)l * FFn * En, b2 + (size_t)l * En, nullptr, x, En, FFn);
  }
  kln<<<Mn / 4, 256, 0, stream>>>(x, lnf_g, lnf_b, h);
  kgemm8<8, 1, 0, 2><<<dim3(8, 32), 512, 0, stream>>>(
      h, wlmT, blm, outf, nullptr, Vn, En);
}

// Round 24
// 596.369 us; speedup vs baseline: 1.0086x; 1.0086x over previous
//
#include <hip/hip_runtime.h>
#include <hip/hip_bf16.h>
#include <stdint.h>

typedef __hip_bfloat16 bf16;
typedef __attribute__((ext_vector_type(8))) short bf16x8;
typedef __attribute__((ext_vector_type(8))) short short8;
typedef __attribute__((ext_vector_type(4))) float f32x4;

#define DEV __device__ __forceinline__

static constexpr int Bn = 16, Tn = 512, En = 512, Hn = 8, Ln = 4, Vn = 2048;
static constexpr int HSn = 64, FFn = 2048, Mn = Bn * Tn;  // M = 8192
static constexpr int SQ = 1536;                           // fused qkv row stride

DEV f32x4 mfma16(bf16x8 a, bf16x8 b, f32x4 c) {
  return __builtin_amdgcn_mfma_f32_16x16x32_bf16(a, b, c, 0, 0, 0);
}
DEV float b2f(bf16 x) { return __bfloat162float(x); }
DEV bf16 f2b(float x) { return __float2bfloat16(x); }
DEV short f2s(float x) { bf16 h = f2b(x); return reinterpret_cast<short&>(h); }
DEV float s2f(short x) { return __bfloat162float(reinterpret_cast<bf16&>(x)); }

// async global->LDS, 16B per lane; LDS dest = base + lane*16 (wave-uniform base).
DEV void gload16(const void* g, void* l) {
  __builtin_amdgcn_global_load_lds(
      (const __attribute__((address_space(1))) void*)(uintptr_t)g,
      (__attribute__((address_space(3))) void*)(uint32_t)(uintptr_t)l, 16, 0, 0);
}

// ------------- merged prep: weight transposes + rel cast + embedding -------------
// blocks [0,13312): transpose+cast tiles; [13312,14335): rel cast; [14335,16383): embed.
__global__ __launch_bounds__(256) void kprep(
    const float* __restrict__ Wq, const float* __restrict__ Wk,
    const float* __restrict__ Wv, const float* __restrict__ Wo,
    const float* __restrict__ W1, const float* __restrict__ W2,
    const float* __restrict__ Wlm, const float* __restrict__ rel,
    const int* __restrict__ idx, const float* __restrict__ tok,
    const float* __restrict__ pos,
    bf16* __restrict__ wqkvT, bf16* __restrict__ woT, bf16* __restrict__ w1T,
    bf16* __restrict__ w2T, bf16* __restrict__ wlmT, bf16* __restrict__ relc,
    bf16* __restrict__ x) {
  int id = blockIdx.x;
  if (id < 13312) {
    const float* in;
    bf16* out;
    int R, C, z, cx, cy;
    long in_zs, out_zs;
    if (id < 3072) {  // Wq|Wk|Wv -> wqkvT (out row-stride via out_zs=SQ*En per layer)
      int part = id >> 10, inner = id & 1023;
      z = inner >> 8;
      int tile = inner & 255;
      cx = tile & 15; cy = tile >> 4;
      in = part == 0 ? Wq : (part == 1 ? Wk : Wv);
      out = wqkvT + part * 512 * 512;
      R = En; C = En; in_zs = (long)En * En; out_zs = (long)SQ * En;
    } else if (id < 4096) {
      int inner = id - 3072;
      z = inner >> 8;
      int tile = inner & 255;
      cx = tile & 15; cy = tile >> 4;
      in = Wo; out = woT; R = En; C = En;
      in_zs = (long)En * En; out_zs = (long)En * En;
    } else if (id < 8192) {
      int inner = id - 4096;
      z = inner >> 10;
      int tile = inner & 1023;
      cx = tile & 63; cy = tile >> 6;
      in = W1; out = w1T; R = En; C = FFn;
      in_zs = (long)En * FFn; out_zs = (long)En * FFn;
    } else if (id < 12288) {
      int inner = id - 8192;
      z = inner >> 10;
      int tile = inner & 1023;
      cx = tile & 15; cy = tile >> 4;
      in = W2; out = w2T; R = FFn; C = En;
      in_zs = (long)FFn * En; out_zs = (long)FFn * En;
    } else {
      int tile = id - 12288;
      z = 0;
      cx = tile & 63; cy = tile >> 6;
      in = Wlm; out = wlmT; R = En; C = Vn;
      in_zs = 0; out_zs = 0;
    }
    __shared__ float tile_s[32][33];
    int tx = threadIdx.x & 31, ty = threadIdx.x >> 5;
    const float* inz = in + (size_t)z * in_zs;
    bf16* outz = out + (size_t)z * out_zs;
    int c0 = cx * 32, r0 = cy * 32;
    for (int k = 0; k < 32; k += 8)
      tile_s[ty + k][tx] = inz[(size_t)(r0 + ty + k) * C + (c0 + tx)];
    __syncthreads();
    for (int k = 0; k < 32; k += 8)
      outz[(size_t)(c0 + ty + k) * R + (r0 + tx)] = f2b(tile_s[tx][ty + k]);
  } else if (id < 14335) {
    int i = (id - 13312) * 256 + threadIdx.x;  // exactly covers 261888
    relc[i] = f2b(rel[i]);
  } else {
    int i = (id - 14335) * 256 + threadIdx.x;  // over M*E/8
    int e8 = (i & 63) * 8;
    int bt = i >> 6;
    int t = bt & (Tn - 1);
    const float* tp = tok + (size_t)idx[bt] * En + e8;
    const float* pp = pos + (size_t)t * En + e8;
    f32x4 t0 = *(const f32x4*)tp, t1 = *(const f32x4*)(tp + 4);
    f32x4 p0 = *(const f32x4*)pp, p1 = *(const f32x4*)(pp + 4);
    short8 ov;
    for (int j = 0; j < 4; j++) {
      ov[j] = f2s(t0[j] + p0[j]);
      ov[j + 4] = f2s(t1[j] + p1[j]);
    }
    *(short8*)(x + (size_t)bt * En + e8) = ov;
  }
}

// ------------- LayerNorm (bf16 x): 4 rows/block, wave per row -------------
__global__ __launch_bounds__(256) void kln(const bf16* __restrict__ x,
                                           const float* __restrict__ g,
                                           const float* __restrict__ b,
                                           bf16* __restrict__ out) {
  int row = blockIdx.x * 4 + (threadIdx.x >> 6);
  int lane = threadIdx.x & 63;
  short8 xv = *(const short8*)(x + (size_t)row * En + lane * 8);
  float v[8], s = 0.f;
  for (int j = 0; j < 8; j++) { v[j] = s2f(xv[j]); s += v[j]; }
  for (int m = 1; m < 64; m <<= 1) s += __shfl_xor(s, m);
  float mean = s * (1.f / En);
  float s2 = 0.f;
  for (int j = 0; j < 8; j++) { float d = v[j] - mean; s2 += d * d; }
  for (int m = 1; m < 64; m <<= 1) s2 += __shfl_xor(s2, m);
  float rstd = rsqrtf(s2 * (1.f / En) + 1e-5f);
  f32x4 g0 = *(const f32x4*)(g + lane * 8), g1 = *(const f32x4*)(g + lane * 8 + 4);
  f32x4 b0 = *(const f32x4*)(b + lane * 8), b1 = *(const f32x4*)(b + lane * 8 + 4);
  short8 ov;
  for (int j = 0; j < 4; j++) {
    ov[j] = f2s((v[j] - mean) * rstd * g0[j] + b0[j]);
    ov[j + 4] = f2s((v[j + 4] - mean) * rstd * g1[j] + b1[j]);
  }
  *(short8*)(out + (size_t)row * En + lane * 8) = ov;
}

// ------------- GEMM (2-phase): C = A[M,K] @ Bt[N,K]^T, BMxBN, BK=64 ------
// MODE: 0 bf16 store outh; 1 bf16 residual += outh; 2 fp32 store outf.
template <int BM, int BN, int TW, int DB, int SWZ, int NBIAS, int RELU, int MODE>
__global__ __launch_bounds__(TW) void kgemm(const bf16* __restrict__ A,
                                            const bf16* __restrict__ Bt,
                                            const float* __restrict__ bias,
                                            float* __restrict__ outf,
                                            bf16* __restrict__ outh, int Ndim, int K) {
  constexpr int NW = TW / 64;
  constexpr int WCN = NW / 2;
  constexpr int WM = BM / 2, WN = BN / WCN, MI = WM / 16, NI = WN / 16;
  constexpr int NB = DB ? 2 : 1;
  __shared__ bf16 As[NB][BM * 64];
  __shared__ bf16 Bs[NB][BN * 64];
  int t = threadIdx.x, lane = t & 63, w = t >> 6;
  int lr = lane & 15, lg = lane >> 4;
  int sx = lr & 7;
  int wr = w / WCN, wc = w % WCN;
  int bx, by;
  if (SWZ) {
    int id = blockIdx.x + gridDim.x * blockIdx.y;
    int xcd = id & 7, s = id >> 3;
    int gx = gridDim.x;
    by = xcd * 8 + s / gx;
    bx = s % gx;
  } else {
    bx = blockIdx.x; by = blockIdx.y;
  }
  int br = by * BM, bc = bx * BN;
  f32x4 acc[MI][NI] = {};
  int rl = lane >> 3, cb = (lane & 7) ^ rl;
  const bf16* Abase = A + (size_t)(br + w * (BM / NW) + rl) * K + cb * 8;
  const bf16* Bbase = Bt + (size_t)(bc + w * (BN / NW) + rl) * K + cb * 8;

  auto STAGE = [&](int buf, int kt) {
    for (int c = 0; c < BM / (8 * NW); c++)
      gload16(Abase + (size_t)(c * 8) * K + kt, &As[buf][(w * (BM / NW) + c * 8) * 64]);
    for (int c = 0; c < BN / (8 * NW); c++)
      gload16(Bbase + (size_t)(c * 8) * K + kt, &Bs[buf][(w * (BN / NW) + c * 8) * 64]);
  };
  auto COMPUTE = [&](int buf) {
    for (int kk = 0; kk < 2; kk++) {
      int gb = (kk * 4 + lg) ^ sx;
      bf16x8 af[MI], bfr[NI];
      for (int mi = 0; mi < MI; mi++)
        af[mi] = *(const bf16x8*)&As[buf][(wr * WM + mi * 16 + lr) * 64 + gb * 8];
      for (int ni = 0; ni < NI; ni++)
        bfr[ni] = *(const bf16x8*)&Bs[buf][(wc * WN + ni * 16 + lr) * 64 + gb * 8];
      for (int mi = 0; mi < MI; mi++)
        for (int ni = 0; ni < NI; ni++)
          acc[mi][ni] = mfma16(af[mi], bfr[ni], acc[mi][ni]);
    }
  };

  if (DB) {
    STAGE(0, 0);
    __syncthreads();
    int nt = K / 64;
    for (int t2 = 0; t2 < nt; t2++) {
      int cur = t2 & 1;
      if (t2 + 1 < nt) STAGE(cur ^ 1, (t2 + 1) * 64);
      COMPUTE(cur);
      __syncthreads();
    }
  } else {
    for (int kt = 0; kt < K; kt += 64) {
      __syncthreads();
      STAGE(0, kt);
      __syncthreads();
      COMPUTE(0);
    }
  }

  for (int mi = 0; mi < MI; mi++)
    for (int ni = 0; ni < NI; ni++)
      for (int r = 0; r < 4; r++) {
        int row = br + wr * WM + mi * 16 + lg * 4 + r;
        int col = bc + wc * WN + ni * 16 + lr;
        float val = acc[mi][ni][r];
        if (NBIAS) val += bias[col];
        if (RELU) val = fmaxf(val, 0.f);
        if (MODE == 1) {
          bf16* p = outh + (size_t)row * Ndim + col;
          *p = f2b(b2f(*p) + val);
        } else if (MODE == 2) {
          outf[(size_t)row * Ndim + col] = val;
        } else {
          outh[(size_t)row * Ndim + col] = f2b(val);
        }
      }
}

// ------------- GEMM (8-phase counted-vmcnt): 256x256, BK=64, 512 thr ------
// Raw asm barriers; counted vmcnt; grid (8,32) [N=2048, M=8192]; K/64 >= 2.
// MODE: 0 bf16 store; 2 fp32 store.
template <int NBIAS, int RELU, int MODE>
__global__ __launch_bounds__(512) void kgemm8(const bf16* __restrict__ A,
                                              const bf16* __restrict__ Bt,
                                              const float* __restrict__ bias,
                                              float* __restrict__ outf,
                                              bf16* __restrict__ outh, int Ndim, int K) {
  __shared__ bf16 As[2][256 * 64];
  __shared__ bf16 Bs[2][256 * 64];
  int t = threadIdx.x, lane = t & 63, w = t >> 6;
  int lr = lane & 15, lg = lane >> 4;
  int sx = lr & 7;
  int wr = w >> 2, wc = w & 3;
  int rl8 = lane >> 3, cb = (lane & 7) ^ rl8;
  int id = blockIdx.x + gridDim.x * blockIdx.y;  // grid (8,32)
  int xcd = id & 7, s = id >> 3;
  int by = xcd * 4 + (s >> 3), bx = s & 7;       // bijective XCD panel swizzle
  int br = by * 256, bc = bx * 256;
  f32x4 acc[8][4] = {};
  const bf16* Abase = A + (size_t)(br + w * 16 + rl8) * K + cb * 8;
  const bf16* Bbase = Bt + (size_t)(bc + w * 16 + rl8) * K + cb * 8;

  auto STAGEH = [&](int hh, int buf, int kt) {
    int half = hh & 1;
    if (hh < 2) {
      const bf16* g = Abase + (size_t)(half * 128) * K + kt;
      bf16* l = &As[buf][(half * 128 + w * 16) * 64];
      gload16(g, l);
      gload16(g + (size_t)8 * K, l + 8 * 64);
    } else {
      const bf16* g = Bbase + (size_t)(half * 128) * K + kt;
      bf16* l = &Bs[buf][(half * 128 + w * 16) * 64];
      gload16(g, l);
      gload16(g + (size_t)8 * K, l + 8 * 64);
    }
  };

#define PHASE8(Q, P)                                                          \
  do {                                                                        \
    constexpr int mh = (Q) >> 1, nh = (Q) & 1;                                \
    bf16x8 af[4][2], bfr[2][2];                                               \
    _Pragma("unroll") for (int kk = 0; kk < 2; kk++) {                        \
      int gb = (kk * 4 + lg) ^ sx;                                            \
      _Pragma("unroll") for (int i = 0; i < 4; i++)                           \
        af[i][kk] = *(const bf16x8*)&As[P][(wr * 128 + (mh * 4 + i) * 16 + lr) * 64 + gb * 8]; \
      _Pragma("unroll") for (int j = 0; j < 2; j++)                           \
        bfr[j][kk] = *(const bf16x8*)&Bs[P][(wc * 64 + (nh * 2 + j) * 16 + lr) * 64 + gb * 8]; \
    }                                                                         \
    __builtin_amdgcn_s_setprio(1);                                            \
    _Pragma("unroll") for (int i = 0; i < 4; i++)                             \
      _Pragma("unroll") for (int j = 0; j < 2; j++) {                         \
        acc[mh * 4 + i][nh * 2 + j] =                                         \
            mfma16(af[i][0], bfr[j][0], acc[mh * 4 + i][nh * 2 + j]);         \
        acc[mh * 4 + i][nh * 2 + j] =                                         \
            mfma16(af[i][1], bfr[j][1], acc[mh * 4 + i][nh * 2 + j]);         \
      }                                                                       \
    __builtin_amdgcn_s_setprio(0);                                            \
  } while (0)

  int nt = K / 64;  // >= 2 required
  for (int hh = 0; hh < 4; hh++) STAGEH(hh, 0, 0);
  STAGEH(0, 1, 64);
  STAGEH(1, 1, 64);
  asm volatile("s_waitcnt vmcnt(4)" ::: "memory");
  asm volatile("s_barrier" ::: "memory");
  for (int t2 = 0; t2 < nt; t2++) {
    int p = t2 & 1;
    if (t2 + 1 < nt) STAGEH(2, p ^ 1, (t2 + 1) * 64);
    PHASE8(0, p);
    if (t2 + 1 < nt) STAGEH(3, p ^ 1, (t2 + 1) * 64);
    PHASE8(1, p);
    PHASE8(2, p);
    PHASE8(3, p);
    asm volatile("s_barrier" ::: "memory");
    if (t2 + 2 < nt) {
      STAGEH(0, p, (t2 + 2) * 64);
      STAGEH(1, p, (t2 + 2) * 64);
      asm volatile("s_waitcnt vmcnt(4)" ::: "memory");
      asm volatile("s_barrier" ::: "memory");
    } else if (t2 + 1 < nt) {
      asm volatile("s_waitcnt vmcnt(0)" ::: "memory");
      asm volatile("s_barrier" ::: "memory");
    }
  }
#undef PHASE8
#pragma unroll
  for (int mi = 0; mi < 8; mi++)
#pragma unroll
    for (int ni = 0; ni < 4; ni++)
#pragma unroll
      for (int r = 0; r < 4; r++) {
        int row = br + wr * 128 + mi * 16 + lg * 4 + r;
        int col = bc + wc * 64 + ni * 16 + lr;
        float val = acc[mi][ni][r];
        if (NBIAS) val += bias[col];
        if (RELU) val = fmaxf(val, 0.f);
        if (MODE == 2) outf[(size_t)row * Ndim + col] = val;
        else outh[(size_t)row * Ndim + col] = f2b(val);
      }
}

// ------------- fused causal attention, 8-wave paired i-blocks (R14/R16-proven) ------
__global__ __launch_bounds__(512) void kattn(const bf16* __restrict__ qkv,
                                             const bf16* __restrict__ rel,
                                             bf16* __restrict__ ctx) {
  __shared__ bf16 Ks[128 * 64];       // [j][d], col-block XOR (j&7)
  __shared__ bf16 Vs[64 * 128];       // [d][j], col-block (j>>3) XOR (d&7)
  __shared__ bf16 Prel[8][16 * 81];   // per-wave rel panel [ii][m], stride 81
  __shared__ bf16 Ps[8][16 * 64];     // per-wave P [i][j]
  int pairp = blockIdx.x, bh = blockIdx.y;
  int b = bh >> 3, hh = bh & 7;
  int t = threadIdx.x, lane = t & 63, w = t >> 6;   // w in [0,8)
  int wl = w & 3, wg = w >> 2;                      // quarter, group
  int lr = lane & 15, lg = lane >> 4;
  int sx = lr & 7;
  int rl8 = lane >> 3, cbk = (lane & 7) ^ rl8;
  const size_t headrow = (size_t)(b * Tn + hh * 64);
  bf16* prw = &Prel[w][0];
  bf16* psw = &Ps[w][0];
  int jp = t >> 3, db = (t & 7) * 8;  // V staging: rows jp*2, jp*2+1

  int ia = pairp, ib = 7 - pairp;
  int myblk = wg ? ia : ib;
  int mylast = myblk * 64;
  int i0w = myblk * 64 + wl * 16;
  bf16x8 aq[2];
  {
    int t2 = i0w + lr;
    const bf16* qp = qkv + (headrow + (t2 >> 3)) * SQ + (t2 & 7) * 64;
    aq[0] = *(const bf16x8*)(qp + lg * 8);
    aq[1] = *(const bf16x8*)(qp + 32 + lg * 8);
  }
  f32x4 o[4] = {};
  float m_run = -3e38f, l_run = 0.f;
  int ntiles = (ib >> 1) + 1;

  auto SUBTILE = [&](int jb, bool diag, int su) {
    int njmax = diag ? wl : 3;
    int nmmin = diag ? 3 - wl : 0;
    __builtin_amdgcn_s_setprio(1);
    f32x4 sqk[4] = {};
    for (int nj = 0; nj <= njmax; nj++) {
      int row = su * 64 + nj * 16 + lr;
      bf16x8 kb0 = *(const bf16x8*)&Ks[row * 64 + ((lg ^ sx) * 8)];
      bf16x8 kb1 = *(const bf16x8*)&Ks[row * 64 + (((4 + lg) ^ sx) * 8)];
      sqk[nj] = mfma16(kb0, aq[0], sqk[nj]);
      sqk[nj] = mfma16(kb1, aq[1], sqk[nj]);
    }
    int base = i0w - jb + 448;
    for (int nm = nmmin; nm < 5; nm++) {
      int mrow = base + nm * 16 + lr;
      if (mrow > 1022) mrow = 1022;
      const bf16* rp = rel + (size_t)mrow * 64;
      f32x4 sr = {};
      sr = mfma16(aq[0], *(const bf16x8*)(rp + lg * 8), sr);
      sr = mfma16(aq[1], *(const bf16x8*)(rp + 32 + lg * 8), sr);
      for (int r = 0; r < 4; r++)
        prw[(lg * 4 + r) * 81 + nm * 16 + lr] = f2b(sr[r]);
    }
    __builtin_amdgcn_s_setprio(0);
    float sv[4][4];
    for (int nj = 0; nj < 4; nj++)
      for (int r = 0; r < 4; r++) sv[nj][r] = -3e38f;
    float mloc = -3e38f;
    for (int nj = 0; nj <= njmax; nj++)
      for (int r = 0; r < 4; r++) {
        int jj = nj * 16 + lg * 4 + r;
        float val = sqk[nj][r] * 0.125f + b2f(prw[lr * 81 + (lr - jj + 63)]);
        if (jb + jj > i0w + lr) val = -3e38f;
        sv[nj][r] = val;
        mloc = fmaxf(mloc, val);
      }
    mloc = fmaxf(mloc, __shfl_xor(mloc, 16));
    mloc = fmaxf(mloc, __shfl_xor(mloc, 32));
    float mnew = fmaxf(m_run, mloc);
    float corr = __expf(m_run - mnew);
    m_run = mnew;
    float lsum = 0.f;
    for (int nj = 0; nj < 4; nj++)
      for (int r = 0; r < 4; r++) {
        float p = __expf(sv[nj][r] - mnew);
        lsum += p;
        psw[lr * 64 + (((nj * 2 + (lg >> 1)) ^ sx) * 8) + (lg & 1) * 4 + r] = f2b(p);
      }
    lsum += __shfl_xor(lsum, 16);
    lsum += __shfl_xor(lsum, 32);
    l_run = l_run * corr + lsum;
    for (int r = 0; r < 4; r++) {
      float c = __shfl(corr, lg * 4 + r);
      for (int nd = 0; nd < 4; nd++) o[nd][r] *= c;
    }
    __builtin_amdgcn_s_setprio(1);
    bf16x8 ap0 = *(const bf16x8*)&psw[lr * 64 + ((lg ^ sx) * 8)];
    bf16x8 ap1 = *(const bf16x8*)&psw[lr * 64 + (((4 + lg) ^ sx) * 8)];
    for (int nd = 0; nd < 4; nd++) {
      int d = nd * 16 + lr;
      bf16x8 vb0 = *(const bf16x8*)&Vs[d * 128 + ((su * 8 + (lg ^ sx)) * 8)];
      bf16x8 vb1 = *(const bf16x8*)&Vs[d * 128 + ((su * 8 + ((4 + lg) ^ sx)) * 8)];
      o[nd] = mfma16(ap0, vb0, o[nd]);
      o[nd] = mfma16(ap1, vb1, o[nd]);
    }
    __builtin_amdgcn_s_setprio(0);
  };

  for (int jt = 0; jt < ntiles; jt++) {
    int jbase = jt * 128;
    bf16x8 vv[2];
#pragma unroll
    for (int u = 0; u < 2; u++) {
      int j0 = jbase + jp * 2 + u;
      vv[u] = *(const bf16x8*)(qkv + (headrow + (j0 >> 3)) * SQ + (j0 & 7) * 64 + 1024 + db);
    }
    __syncthreads();  // previous-iter readers done
#pragma unroll
    for (int c = 0; c < 2; c++) {
      int row = w * 16 + c * 8 + rl8;
      const bf16* src = qkv + (headrow + ((jbase + row) >> 3)) * SQ +
                        (row & 7) * 64 + 512 + cbk * 8;
      gload16(src, &Ks[(w * 16 + c * 8) * 64]);
    }
    // V transpose into LDS: one paired-b32 store set per thread
    {
      const short* pa = (const short*)&vv[0];
      const short* pb = (const short*)&vv[1];
      int j0 = jp * 2;
      int jblk = j0 >> 3, jin = j0 & 7;
#pragma unroll
      for (int u = 0; u < 8; u++) {
        int d = db + u;
        int idx = d * 128 + ((jblk ^ (d & 7)) * 8) + jin;
        uint32_t pk = (uint32_t)(uint16_t)pa[u] | ((uint32_t)(uint16_t)pb[u] << 16);
        *(uint32_t*)((short*)Vs + idx) = pk;
      }
    }
    __syncthreads();
#pragma unroll
    for (int su = 0; su < 2; su++) {
      int jb = jbase + su * 64;
      if (jb > ib * 64) break;                  // block-uniform
      if (jb <= mylast) SUBTILE(jb, jb == mylast, su);
    }
  }  // jt
  for (int r = 0; r < 4; r++) {
    float linv = 1.f / __shfl(l_run, lg * 4 + r);
    int row = i0w + lg * 4 + r;
    for (int nd = 0; nd < 4; nd++)
      ctx[((size_t)b * Tn + row) * En + hh * 64 + nd * 16 + lr] = f2b(o[nd][r] * linv);
  }
}

// ------------- launch -------------
extern "C" void kernel_launch(void* const* d_in, const int* in_sizes, int n_in,
                              void* d_out, int out_size, void* d_ws, size_t ws_size,
                              hipStream_t stream) {
  (void)in_sizes; (void)n_in; (void)out_size; (void)ws_size;
  const int* idx = (const int*)d_in[0];
  const float* tok = (const float*)d_in[1];
  const float* pos = (const float*)d_in[2];
  const float* Wq = (const float*)d_in[3];
  const float* Wk = (const float*)d_in[4];
  const float* Wv = (const float*)d_in[5];
  const float* rel = (const float*)d_in[6];
  const float* Wo = (const float*)d_in[7];
  const float* bo = (const float*)d_in[8];
  const float* ln1_g = (const float*)d_in[9];
  const float* ln1_b = (const float*)d_in[10];
  const float* W1 = (const float*)d_in[11];
  const float* b1 = (const float*)d_in[12];
  const float* W2 = (const float*)d_in[13];
  const float* b2 = (const float*)d_in[14];
  const float* ln2_g = (const float*)d_in[15];
  const float* ln2_b = (const float*)d_in[16];
  const float* lnf_g = (const float*)d_in[17];
  const float* lnf_b = (const float*)d_in[18];
  const float* Wlm = (const float*)d_in[19];
  const float* blm = (const float*)d_in[20];

  char* ws = (char*)d_ws;
  bf16* x = (bf16*)(ws + 0);                 // 8 MB bf16 residual
  bf16* h = (bf16*)(ws + 16777216);          // 8 MB LN out
  bf16* qkv = (bf16*)(ws + 25165824);        // 24 MB fused q|k|v [M][1536]
  bf16* ctx = (bf16*)(ws + 50331648);        // 8 MB
  bf16* ffn1 = qkv;                          // 32 MB alias over qkv+ctx
  bf16* wqkvT = (bf16*)(ws + 58720256);      // [L][1536][512]
  bf16* woT = wqkvT + (size_t)Ln * SQ * En;
  bf16* w1T = woT + (size_t)Ln * En * En;
  bf16* w2T = w1T + (size_t)Ln * En * FFn;
  bf16* wlmT = w2T + (size_t)Ln * FFn * En;
  bf16* relc = wlmT + (size_t)En * Vn;
  float* outf = (float*)d_out;

  kprep<<<16383, 256, 0, stream>>>(Wq, Wk, Wv, Wo, W1, W2, Wlm, rel, idx, tok, pos,
                                   wqkvT, woT, w1T, w2T, wlmT, relc, x);

  for (int l = 0; l < Ln; l++) {
    kln<<<Mn / 4, 256, 0, stream>>>(x, ln1_g + (size_t)l * En, ln1_b + (size_t)l * En, h);
    kgemm<128, 128, 256, 0, 1, 0, 0, 0><<<dim3(12, 64), 256, 0, stream>>>(
        h, wqkvT + (size_t)l * SQ * En, nullptr, nullptr, qkv, SQ, En);
    kattn<<<dim3(4, 128), 512, 0, stream>>>(
        qkv, relc + (size_t)l * (2 * Tn - 1) * HSn, ctx);
    kgemm<128, 128, 512, 1, 1, 1, 0, 1><<<dim3(4, 64), 512, 0, stream>>>(
        ctx, woT + (size_t)l * En * En, bo + (size_t)l * En, nullptr, x, En, En);
    kln<<<Mn / 4, 256, 0, stream>>>(x, ln2_g + (size_t)l * En, ln2_b + (size_t)l * En, h);
    kgemm8<1, 1, 0><<<dim3(8, 32), 512, 0, stream>>>(
        h, w1T + (size_t)l * En * FFn, b1 + (size_t)l * FFn, nullptr, ffn1, FFn, En);
    kgemm<128, 128, 512, 1, 1, 1, 0, 1><<<dim3(4, 64), 512, 0, stream>>>(
        ffn1, w2T + (size_t)l * FFn * En, b2 + (size_t)l * En, nullptr, x, En, FFn);
  }
  kln<<<Mn / 4, 256, 0, stream>>>(x, lnf_g, lnf_b, h);
  kgemm8<1, 0, 2><<<dim3(8, 32), 512, 0, stream>>>(
      h, wlmT, blm, outf, nullptr, Vn, En);
}

// Round 25
// 584.069 us; speedup vs baseline: 1.0299x; 1.0211x over previous
//
#include <hip/hip_runtime.h>
#include <hip/hip_bf16.h>
#include <stdint.h>

typedef __hip_bfloat16 bf16;
typedef __attribute__((ext_vector_type(8))) short bf16x8;
typedef __attribute__((ext_vector_type(8))) short short8;
typedef __attribute__((ext_vector_type(4))) float f32x4;

#define DEV __device__ __forceinline__

static constexpr int Bn = 16, Tn = 512, En = 512, Hn = 8, Ln = 4, Vn = 2048;
static constexpr int HSn = 64, FFn = 2048, Mn = Bn * Tn;  // M = 8192
static constexpr int SQ = 1536;                           // fused qkv row stride

DEV f32x4 mfma16(bf16x8 a, bf16x8 b, f32x4 c) {
  return __builtin_amdgcn_mfma_f32_16x16x32_bf16(a, b, c, 0, 0, 0);
}
DEV float b2f(bf16 x) { return __bfloat162float(x); }
DEV bf16 f2b(float x) { return __float2bfloat16(x); }
DEV short f2s(float x) { bf16 h = f2b(x); return reinterpret_cast<short&>(h); }
DEV float s2f(short x) { return __bfloat162float(reinterpret_cast<bf16&>(x)); }

// async global->LDS, 16B per lane; LDS dest = base + lane*16 (wave-uniform base).
DEV void gload16(const void* g, void* l) {
  __builtin_amdgcn_global_load_lds(
      (const __attribute__((address_space(1))) void*)(uintptr_t)g,
      (__attribute__((address_space(3))) void*)(uint32_t)(uintptr_t)l, 16, 0, 0);
}

// ------------- merged prep: weight transposes + rel cast + embedding -------------
// blocks [0,13312): transpose+cast tiles; [13312,14335): rel cast; [14335,16383): embed.
__global__ __launch_bounds__(256) void kprep(
    const float* __restrict__ Wq, const float* __restrict__ Wk,
    const float* __restrict__ Wv, const float* __restrict__ Wo,
    const float* __restrict__ W1, const float* __restrict__ W2,
    const float* __restrict__ Wlm, const float* __restrict__ rel,
    const int* __restrict__ idx, const float* __restrict__ tok,
    const float* __restrict__ pos,
    bf16* __restrict__ wqkvT, bf16* __restrict__ woT, bf16* __restrict__ w1T,
    bf16* __restrict__ w2T, bf16* __restrict__ wlmT, bf16* __restrict__ relc,
    bf16* __restrict__ x) {
  int id = blockIdx.x;
  if (id < 13312) {
    const float* in;
    bf16* out;
    int R, C, z, cx, cy;
    long in_zs, out_zs;
    if (id < 3072) {  // Wq|Wk|Wv -> wqkvT (out row-stride via out_zs=SQ*En per layer)
      int part = id >> 10, inner = id & 1023;
      z = inner >> 8;
      int tile = inner & 255;
      cx = tile & 15; cy = tile >> 4;
      in = part == 0 ? Wq : (part == 1 ? Wk : Wv);
      out = wqkvT + part * 512 * 512;
      R = En; C = En; in_zs = (long)En * En; out_zs = (long)SQ * En;
    } else if (id < 4096) {
      int inner = id - 3072;
      z = inner >> 8;
      int tile = inner & 255;
      cx = tile & 15; cy = tile >> 4;
      in = Wo; out = woT; R = En; C = En;
      in_zs = (long)En * En; out_zs = (long)En * En;
    } else if (id < 8192) {
      int inner = id - 4096;
      z = inner >> 10;
      int tile = inner & 1023;
      cx = tile & 63; cy = tile >> 6;
      in = W1; out = w1T; R = En; C = FFn;
      in_zs = (long)En * FFn; out_zs = (long)En * FFn;
    } else if (id < 12288) {
      int inner = id - 8192;
      z = inner >> 10;
      int tile = inner & 1023;
      cx = tile & 15; cy = tile >> 4;
      in = W2; out = w2T; R = FFn; C = En;
      in_zs = (long)FFn * En; out_zs = (long)FFn * En;
    } else {
      int tile = id - 12288;
      z = 0;
      cx = tile & 63; cy = tile >> 6;
      in = Wlm; out = wlmT; R = En; C = Vn;
      in_zs = 0; out_zs = 0;
    }
    __shared__ float tile_s[32][33];
    int tx = threadIdx.x & 31, ty = threadIdx.x >> 5;
    const float* inz = in + (size_t)z * in_zs;
    bf16* outz = out + (size_t)z * out_zs;
    int c0 = cx * 32, r0 = cy * 32;
    for (int k = 0; k < 32; k += 8)
      tile_s[ty + k][tx] = inz[(size_t)(r0 + ty + k) * C + (c0 + tx)];
    __syncthreads();
    for (int k = 0; k < 32; k += 8)
      outz[(size_t)(c0 + ty + k) * R + (r0 + tx)] = f2b(tile_s[tx][ty + k]);
  } else if (id < 14335) {
    int i = (id - 13312) * 256 + threadIdx.x;  // exactly covers 261888
    relc[i] = f2b(rel[i]);
  } else {
    int i = (id - 14335) * 256 + threadIdx.x;  // over M*E/8
    int e8 = (i & 63) * 8;
    int bt = i >> 6;
    int t = bt & (Tn - 1);
    const float* tp = tok + (size_t)idx[bt] * En + e8;
    const float* pp = pos + (size_t)t * En + e8;
    f32x4 t0 = *(const f32x4*)tp, t1 = *(const f32x4*)(tp + 4);
    f32x4 p0 = *(const f32x4*)pp, p1 = *(const f32x4*)(pp + 4);
    short8 ov;
    for (int j = 0; j < 4; j++) {
      ov[j] = f2s(t0[j] + p0[j]);
      ov[j + 4] = f2s(t1[j] + p1[j]);
    }
    *(short8*)(x + (size_t)bt * En + e8) = ov;
  }
}

// ------------- LayerNorm (bf16 x): 4 rows/block, wave per row -------------
__global__ __launch_bounds__(256) void kln(const bf16* __restrict__ x,
                                           const float* __restrict__ g,
                                           const float* __restrict__ b,
                                           bf16* __restrict__ out) {
  int row = blockIdx.x * 4 + (threadIdx.x >> 6);
  int lane = threadIdx.x & 63;
  short8 xv = *(const short8*)(x + (size_t)row * En + lane * 8);
  float v[8], s = 0.f;
  for (int j = 0; j < 8; j++) { v[j] = s2f(xv[j]); s += v[j]; }
  for (int m = 1; m < 64; m <<= 1) s += __shfl_xor(s, m);
  float mean = s * (1.f / En);
  float s2 = 0.f;
  for (int j = 0; j < 8; j++) { float d = v[j] - mean; s2 += d * d; }
  for (int m = 1; m < 64; m <<= 1) s2 += __shfl_xor(s2, m);
  float rstd = rsqrtf(s2 * (1.f / En) + 1e-5f);
  f32x4 g0 = *(const f32x4*)(g + lane * 8), g1 = *(const f32x4*)(g + lane * 8 + 4);
  f32x4 b0 = *(const f32x4*)(b + lane * 8), b1 = *(const f32x4*)(b + lane * 8 + 4);
  short8 ov;
  for (int j = 0; j < 4; j++) {
    ov[j] = f2s((v[j] - mean) * rstd * g0[j] + b0[j]);
    ov[j + 4] = f2s((v[j + 4] - mean) * rstd * g1[j] + b1[j]);
  }
  *(short8*)(out + (size_t)row * En + lane * 8) = ov;
}

// ------------- GEMM (2-phase): C = A[M,K] @ Bt[N,K]^T, BMxBN, BK=64 ------
// MODE: 0 bf16 store outh; 1 bf16 residual += outh; 2 fp32 store outf.
// DB path uses kgemm8-style counted vmcnt: COMPUTE(p) -> s_barrier (p free) ->
// STAGE(p, t+2) -> vmcnt(4) (retires tile t+1, in-order) -> s_barrier.
// Never drains vmcnt to 0 mid-loop; t+2's loads fly across the next compute.
template <int BM, int BN, int TW, int DB, int SWZ, int NBIAS, int RELU, int MODE>
__global__ __launch_bounds__(TW) void kgemm(const bf16* __restrict__ A,
                                            const bf16* __restrict__ Bt,
                                            const float* __restrict__ bias,
                                            float* __restrict__ outf,
                                            bf16* __restrict__ outh, int Ndim, int K) {
  constexpr int NW = TW / 64;
  constexpr int WCN = NW / 2;
  constexpr int WM = BM / 2, WN = BN / WCN, MI = WM / 16, NI = WN / 16;
  constexpr int NB = DB ? 2 : 1;
  __shared__ bf16 As[NB][BM * 64];
  __shared__ bf16 Bs[NB][BN * 64];
  int t = threadIdx.x, lane = t & 63, w = t >> 6;
  int lr = lane & 15, lg = lane >> 4;
  int sx = lr & 7;
  int wr = w / WCN, wc = w % WCN;
  int bx, by;
  if (SWZ) {
    int id = blockIdx.x + gridDim.x * blockIdx.y;
    int xcd = id & 7, s = id >> 3;
    int gx = gridDim.x;
    by = xcd * 8 + s / gx;
    bx = s % gx;
  } else {
    bx = blockIdx.x; by = blockIdx.y;
  }
  int br = by * BM, bc = bx * BN;
  f32x4 acc[MI][NI] = {};
  int rl = lane >> 3, cb = (lane & 7) ^ rl;
  const bf16* Abase = A + (size_t)(br + w * (BM / NW) + rl) * K + cb * 8;
  const bf16* Bbase = Bt + (size_t)(bc + w * (BN / NW) + rl) * K + cb * 8;

  auto STAGE = [&](int buf, int kt) {
    for (int c = 0; c < BM / (8 * NW); c++)
      gload16(Abase + (size_t)(c * 8) * K + kt, &As[buf][(w * (BM / NW) + c * 8) * 64]);
    for (int c = 0; c < BN / (8 * NW); c++)
      gload16(Bbase + (size_t)(c * 8) * K + kt, &Bs[buf][(w * (BN / NW) + c * 8) * 64]);
  };
  auto COMPUTE = [&](int buf) {
    for (int kk = 0; kk < 2; kk++) {
      int gb = (kk * 4 + lg) ^ sx;
      bf16x8 af[MI], bfr[NI];
      for (int mi = 0; mi < MI; mi++)
        af[mi] = *(const bf16x8*)&As[buf][(wr * WM + mi * 16 + lr) * 64 + gb * 8];
      for (int ni = 0; ni < NI; ni++)
        bfr[ni] = *(const bf16x8*)&Bs[buf][(wc * WN + ni * 16 + lr) * 64 + gb * 8];
      for (int mi = 0; mi < MI; mi++)
        for (int ni = 0; ni < NI; ni++)
          acc[mi][ni] = mfma16(af[mi], bfr[ni], acc[mi][ni]);
    }
  };

  if (DB) {
    constexpr int LPS = BM / (8 * NW) + BN / (8 * NW);  // loads/wave/stage
    static_assert(!DB || LPS == 4, "counted vmcnt hardcoded for 4 loads/stage");
    int nt = K / 64;  // >= 2 for all instantiations used
    STAGE(0, 0);
    STAGE(1, 64);
    asm volatile("s_waitcnt vmcnt(4)" ::: "memory");  // tile0 landed; tile1 in flight
    asm volatile("s_barrier" ::: "memory");
    for (int t2 = 0; t2 < nt; t2++) {
      int p = t2 & 1;
      COMPUTE(p);
      asm volatile("s_barrier" ::: "memory");          // all reads of buf p done
      if (t2 + 2 < nt) {
        STAGE(p, (t2 + 2) * 64);
        asm volatile("s_waitcnt vmcnt(4)" ::: "memory");  // tile t+1 landed
        asm volatile("s_barrier" ::: "memory");
      } else if (t2 + 1 < nt) {
        asm volatile("s_waitcnt vmcnt(0)" ::: "memory");  // endgame drain
        asm volatile("s_barrier" ::: "memory");
      }
    }
  } else {
    for (int kt = 0; kt < K; kt += 64) {
      __syncthreads();
      STAGE(0, kt);
      __syncthreads();
      COMPUTE(0);
    }
  }

  for (int mi = 0; mi < MI; mi++)
    for (int ni = 0; ni < NI; ni++)
      for (int r = 0; r < 4; r++) {
        int row = br + wr * WM + mi * 16 + lg * 4 + r;
        int col = bc + wc * WN + ni * 16 + lr;
        float val = acc[mi][ni][r];
        if (NBIAS) val += bias[col];
        if (RELU) val = fmaxf(val, 0.f);
        if (MODE == 1) {
          bf16* p = outh + (size_t)row * Ndim + col;
          *p = f2b(b2f(*p) + val);
        } else if (MODE == 2) {
          outf[(size_t)row * Ndim + col] = val;
        } else {
          outh[(size_t)row * Ndim + col] = f2b(val);
        }
      }
}

// ------------- GEMM (8-phase counted-vmcnt): 256x256, BK=64, 512 thr ------
// Raw asm barriers; counted vmcnt; grid (8,32) [N=2048, M=8192]; K/64 >= 2.
// MODE: 0 bf16 store; 2 fp32 store.
template <int NBIAS, int RELU, int MODE>
__global__ __launch_bounds__(512) void kgemm8(const bf16* __restrict__ A,
                                              const bf16* __restrict__ Bt,
                                              const float* __restrict__ bias,
                                              float* __restrict__ outf,
                                              bf16* __restrict__ outh, int Ndim, int K) {
  __shared__ bf16 As[2][256 * 64];
  __shared__ bf16 Bs[2][256 * 64];
  int t = threadIdx.x, lane = t & 63, w = t >> 6;
  int lr = lane & 15, lg = lane >> 4;
  int sx = lr & 7;
  int wr = w >> 2, wc = w & 3;
  int rl8 = lane >> 3, cb = (lane & 7) ^ rl8;
  int id = blockIdx.x + gridDim.x * blockIdx.y;  // grid (8,32)
  int xcd = id & 7, s = id >> 3;
  int by = xcd * 4 + (s >> 3), bx = s & 7;       // bijective XCD panel swizzle
  int br = by * 256, bc = bx * 256;
  f32x4 acc[8][4] = {};
  const bf16* Abase = A + (size_t)(br + w * 16 + rl8) * K + cb * 8;
  const bf16* Bbase = Bt + (size_t)(bc + w * 16 + rl8) * K + cb * 8;

  auto STAGEH = [&](int hh, int buf, int kt) {
    int half = hh & 1;
    if (hh < 2) {
      const bf16* g = Abase + (size_t)(half * 128) * K + kt;
      bf16* l = &As[buf][(half * 128 + w * 16) * 64];
      gload16(g, l);
      gload16(g + (size_t)8 * K, l + 8 * 64);
    } else {
      const bf16* g = Bbase + (size_t)(half * 128) * K + kt;
      bf16* l = &Bs[buf][(half * 128 + w * 16) * 64];
      gload16(g, l);
      gload16(g + (size_t)8 * K, l + 8 * 64);
    }
  };

#define PHASE8(Q, P)                                                          \
  do {                                                                        \
    constexpr int mh = (Q) >> 1, nh = (Q) & 1;                                \
    bf16x8 af[4][2], bfr[2][2];                                               \
    _Pragma("unroll") for (int kk = 0; kk < 2; kk++) {                        \
      int gb = (kk * 4 + lg) ^ sx;                                            \
      _Pragma("unroll") for (int i = 0; i < 4; i++)                           \
        af[i][kk] = *(const bf16x8*)&As[P][(wr * 128 + (mh * 4 + i) * 16 + lr) * 64 + gb * 8]; \
      _Pragma("unroll") for (int j = 0; j < 2; j++)                           \
        bfr[j][kk] = *(const bf16x8*)&Bs[P][(wc * 64 + (nh * 2 + j) * 16 + lr) * 64 + gb * 8]; \
    }                                                                         \
    __builtin_amdgcn_s_setprio(1);                                            \
    _Pragma("unroll") for (int i = 0; i < 4; i++)                             \
      _Pragma("unroll") for (int j = 0; j < 2; j++) {                         \
        acc[mh * 4 + i][nh * 2 + j] =                                         \
            mfma16(af[i][0], bfr[j][0], acc[mh * 4 + i][nh * 2 + j]);         \
        acc[mh * 4 + i][nh * 2 + j] =                                         \
            mfma16(af[i][1], bfr[j][1], acc[mh * 4 + i][nh * 2 + j]);         \
      }                                                                       \
    __builtin_amdgcn_s_setprio(0);                                            \
  } while (0)

  int nt = K / 64;  // >= 2 required
  for (int hh = 0; hh < 4; hh++) STAGEH(hh, 0, 0);
  STAGEH(0, 1, 64);
  STAGEH(1, 1, 64);
  asm volatile("s_waitcnt vmcnt(4)" ::: "memory");
  asm volatile("s_barrier" ::: "memory");
  for (int t2 = 0; t2 < nt; t2++) {
    int p = t2 & 1;
    if (t2 + 1 < nt) STAGEH(2, p ^ 1, (t2 + 1) * 64);
    PHASE8(0, p);
    if (t2 + 1 < nt) STAGEH(3, p ^ 1, (t2 + 1) * 64);
    PHASE8(1, p);
    PHASE8(2, p);
    PHASE8(3, p);
    asm volatile("s_barrier" ::: "memory");
    if (t2 + 2 < nt) {
      STAGEH(0, p, (t2 + 2) * 64);
      STAGEH(1, p, (t2 + 2) * 64);
      asm volatile("s_waitcnt vmcnt(4)" ::: "memory");
      asm volatile("s_barrier" ::: "memory");
    } else if (t2 + 1 < nt) {
      asm volatile("s_waitcnt vmcnt(0)" ::: "memory");
      asm volatile("s_barrier" ::: "memory");
    }
  }
#undef PHASE8
#pragma unroll
  for (int mi = 0; mi < 8; mi++)
#pragma unroll
    for (int ni = 0; ni < 4; ni++)
#pragma unroll
      for (int r = 0; r < 4; r++) {
        int row = br + wr * 128 + mi * 16 + lg * 4 + r;
        int col = bc + wc * 64 + ni * 16 + lr;
        float val = acc[mi][ni][r];
        if (NBIAS) val += bias[col];
        if (RELU) val = fmaxf(val, 0.f);
        if (MODE == 2) outf[(size_t)row * Ndim + col] = val;
        else outh[(size_t)row * Ndim + col] = f2b(val);
      }
}

// ------------- fused causal attention, 8-wave paired i-blocks (R14/R16-proven) ------
__global__ __launch_bounds__(512) void kattn(const bf16* __restrict__ qkv,
                                             const bf16* __restrict__ rel,
                                             bf16* __restrict__ ctx) {
  __shared__ bf16 Ks[128 * 64];       // [j][d], col-block XOR (j&7)
  __shared__ bf16 Vs[64 * 128];       // [d][j], col-block (j>>3) XOR (d&7)
  __shared__ bf16 Prel[8][16 * 81];   // per-wave rel panel [ii][m], stride 81
  __shared__ bf16 Ps[8][16 * 64];     // per-wave P [i][j]
  int pairp = blockIdx.x, bh = blockIdx.y;
  int b = bh >> 3, hh = bh & 7;
  int t = threadIdx.x, lane = t & 63, w = t >> 6;   // w in [0,8)
  int wl = w & 3, wg = w >> 2;                      // quarter, group
  int lr = lane & 15, lg = lane >> 4;
  int sx = lr & 7;
  int rl8 = lane >> 3, cbk = (lane & 7) ^ rl8;
  const size_t headrow = (size_t)(b * Tn + hh * 64);
  bf16* prw = &Prel[w][0];
  bf16* psw = &Ps[w][0];
  int jp = t >> 3, db = (t & 7) * 8;  // V staging: rows jp*2, jp*2+1

  int ia = pairp, ib = 7 - pairp;
  int myblk = wg ? ia : ib;
  int mylast = myblk * 64;
  int i0w = myblk * 64 + wl * 16;
  bf16x8 aq[2];
  {
    int t2 = i0w + lr;
    const bf16* qp = qkv + (headrow + (t2 >> 3)) * SQ + (t2 & 7) * 64;
    aq[0] = *(const bf16x8*)(qp + lg * 8);
    aq[1] = *(const bf16x8*)(qp + 32 + lg * 8);
  }
  f32x4 o[4] = {};
  float m_run = -3e38f, l_run = 0.f;
  int ntiles = (ib >> 1) + 1;

  auto SUBTILE = [&](int jb, bool diag, int su) {
    int njmax = diag ? wl : 3;
    int nmmin = diag ? 3 - wl : 0;
    __builtin_amdgcn_s_setprio(1);
    f32x4 sqk[4] = {};
    for (int nj = 0; nj <= njmax; nj++) {
      int row = su * 64 + nj * 16 + lr;
      bf16x8 kb0 = *(const bf16x8*)&Ks[row * 64 + ((lg ^ sx) * 8)];
      bf16x8 kb1 = *(const bf16x8*)&Ks[row * 64 + (((4 + lg) ^ sx) * 8)];
      sqk[nj] = mfma16(kb0, aq[0], sqk[nj]);
      sqk[nj] = mfma16(kb1, aq[1], sqk[nj]);
    }
    int base = i0w - jb + 448;
    for (int nm = nmmin; nm < 5; nm++) {
      int mrow = base + nm * 16 + lr;
      if (mrow > 1022) mrow = 1022;
      const bf16* rp = rel + (size_t)mrow * 64;
      f32x4 sr = {};
      sr = mfma16(aq[0], *(const bf16x8*)(rp + lg * 8), sr);
      sr = mfma16(aq[1], *(const bf16x8*)(rp + 32 + lg * 8), sr);
      for (int r = 0; r < 4; r++)
        prw[(lg * 4 + r) * 81 + nm * 16 + lr] = f2b(sr[r]);
    }
    __builtin_amdgcn_s_setprio(0);
    float sv[4][4];
    for (int nj = 0; nj < 4; nj++)
      for (int r = 0; r < 4; r++) sv[nj][r] = -3e38f;
    float mloc = -3e38f;
    for (int nj = 0; nj <= njmax; nj++)
      for (int r = 0; r < 4; r++) {
        int jj = nj * 16 + lg * 4 + r;
        float val = sqk[nj][r] * 0.125f + b2f(prw[lr * 81 + (lr - jj + 63)]);
        if (jb + jj > i0w + lr) val = -3e38f;
        sv[nj][r] = val;
        mloc = fmaxf(mloc, val);
      }
    mloc = fmaxf(mloc, __shfl_xor(mloc, 16));
    mloc = fmaxf(mloc, __shfl_xor(mloc, 32));
    float mnew = fmaxf(m_run, mloc);
    float corr = __expf(m_run - mnew);
    m_run = mnew;
    float lsum = 0.f;
    for (int nj = 0; nj < 4; nj++)
      for (int r = 0; r < 4; r++) {
        float p = __expf(sv[nj][r] - mnew);
        lsum += p;
        psw[lr * 64 + (((nj * 2 + (lg >> 1)) ^ sx) * 8) + (lg & 1) * 4 + r] = f2b(p);
      }
    lsum += __shfl_xor(lsum, 16);
    lsum += __shfl_xor(lsum, 32);
    l_run = l_run * corr + lsum;
    for (int r = 0; r < 4; r++) {
      float c = __shfl(corr, lg * 4 + r);
      for (int nd = 0; nd < 4; nd++) o[nd][r] *= c;
    }
    __builtin_amdgcn_s_setprio(1);
    bf16x8 ap0 = *(const bf16x8*)&psw[lr * 64 + ((lg ^ sx) * 8)];
    bf16x8 ap1 = *(const bf16x8*)&psw[lr * 64 + (((4 + lg) ^ sx) * 8)];
    for (int nd = 0; nd < 4; nd++) {
      int d = nd * 16 + lr;
      bf16x8 vb0 = *(const bf16x8*)&Vs[d * 128 + ((su * 8 + (lg ^ sx)) * 8)];
      bf16x8 vb1 = *(const bf16x8*)&Vs[d * 128 + ((su * 8 + ((4 + lg) ^ sx)) * 8)];
      o[nd] = mfma16(ap0, vb0, o[nd]);
      o[nd] = mfma16(ap1, vb1, o[nd]);
    }
    __builtin_amdgcn_s_setprio(0);
  };

  for (int jt = 0; jt < ntiles; jt++) {
    int jbase = jt * 128;
    bf16x8 vv[2];
#pragma unroll
    for (int u = 0; u < 2; u++) {
      int j0 = jbase + jp * 2 + u;
      vv[u] = *(const bf16x8*)(qkv + (headrow + (j0 >> 3)) * SQ + (j0 & 7) * 64 + 1024 + db);
    }
    __syncthreads();  // previous-iter readers done
#pragma unroll
    for (int c = 0; c < 2; c++) {
      int row = w * 16 + c * 8 + rl8;
      const bf16* src = qkv + (headrow + ((jbase + row) >> 3)) * SQ +
                        (row & 7) * 64 + 512 + cbk * 8;
      gload16(src, &Ks[(w * 16 + c * 8) * 64]);
    }
    // V transpose into LDS: one paired-b32 store set per thread
    {
      const short* pa = (const short*)&vv[0];
      const short* pb = (const short*)&vv[1];
      int j0 = jp * 2;
      int jblk = j0 >> 3, jin = j0 & 7;
#pragma unroll
      for (int u = 0; u < 8; u++) {
        int d = db + u;
        int idx = d * 128 + ((jblk ^ (d & 7)) * 8) + jin;
        uint32_t pk = (uint32_t)(uint16_t)pa[u] | ((uint32_t)(uint16_t)pb[u] << 16);
        *(uint32_t*)((short*)Vs + idx) = pk;
      }
    }
    __syncthreads();
#pragma unroll
    for (int su = 0; su < 2; su++) {
      int jb = jbase + su * 64;
      if (jb > ib * 64) break;                  // block-uniform
      if (jb <= mylast) SUBTILE(jb, jb == mylast, su);
    }
  }  // jt
  for (int r = 0; r < 4; r++) {
    float linv = 1.f / __shfl(l_run, lg * 4 + r);
    int row = i0w + lg * 4 + r;
    for (int nd = 0; nd < 4; nd++)
      ctx[((size_t)b * Tn + row) * En + hh * 64 + nd * 16 + lr] = f2b(o[nd][r] * linv);
  }
}

// ------------- launch -------------
extern "C" void kernel_launch(void* const* d_in, const int* in_sizes, int n_in,
                              void* d_out, int out_size, void* d_ws, size_t ws_size,
                              hipStream_t stream) {
  (void)in_sizes; (void)n_in; (void)out_size; (void)ws_size;
  const int* idx = (const int*)d_in[0];
  const float* tok = (const float*)d_in[1];
  const float* pos = (const float*)d_in[2];
  const float* Wq = (const float*)d_in[3];
  const float* Wk = (const float*)d_in[4];
  const float* Wv = (const float*)d_in[5];
  const float* rel = (const float*)d_in[6];
  const float* Wo = (const float*)d_in[7];
  const float* bo = (const float*)d_in[8];
  const float* ln1_g = (const float*)d_in[9];
  const float* ln1_b = (const float*)d_in[10];
  const float* W1 = (const float*)d_in[11];
  const float* b1 = (const float*)d_in[12];
  const float* W2 = (const float*)d_in[13];
  const float* b2 = (const float*)d_in[14];
  const float* ln2_g = (const float*)d_in[15];
  const float* ln2_b = (const float*)d_in[16];
  const float* lnf_g = (const float*)d_in[17];
  const float* lnf_b = (const float*)d_in[18];
  const float* Wlm = (const float*)d_in[19];
  const float* blm = (const float*)d_in[20];

  char* ws = (char*)d_ws;
  bf16* x = (bf16*)(ws + 0);                 // 8 MB bf16 residual
  bf16* h = (bf16*)(ws + 16777216);          // 8 MB LN out
  bf16* qkv = (bf16*)(ws + 25165824);        // 24 MB fused q|k|v [M][1536]
  bf16* ctx = (bf16*)(ws + 50331648);        // 8 MB
  bf16* ffn1 = qkv;                          // 32 MB alias over qkv+ctx
  bf16* wqkvT = (bf16*)(ws + 58720256);      // [L][1536][512]
  bf16* woT = wqkvT + (size_t)Ln * SQ * En;
  bf16* w1T = woT + (size_t)Ln * En * En;
  bf16* w2T = w1T + (size_t)Ln * En * FFn;
  bf16* wlmT = w2T + (size_t)Ln * FFn * En;
  bf16* relc = wlmT + (size_t)En * Vn;
  float* outf = (float*)d_out;

  kprep<<<16383, 256, 0, stream>>>(Wq, Wk, Wv, Wo, W1, W2, Wlm, rel, idx, tok, pos,
                                   wqkvT, woT, w1T, w2T, wlmT, relc, x);

  for (int l = 0; l < Ln; l++) {
    kln<<<Mn / 4, 256, 0, stream>>>(x, ln1_g + (size_t)l * En, ln1_b + (size_t)l * En, h);
    kgemm<128, 128, 256, 0, 1, 0, 0, 0><<<dim3(12, 64), 256, 0, stream>>>(
        h, wqkvT + (size_t)l * SQ * En, nullptr, nullptr, qkv, SQ, En);
    kattn<<<dim3(4, 128), 512, 0, stream>>>(
        qkv, relc + (size_t)l * (2 * Tn - 1) * HSn, ctx);
    kgemm<128, 128, 512, 1, 1, 1, 0, 1><<<dim3(4, 64), 512, 0, stream>>>(
        ctx, woT + (size_t)l * En * En, bo + (size_t)l * En, nullptr, x, En, En);
    kln<<<Mn / 4, 256, 0, stream>>>(x, ln2_g + (size_t)l * En, ln2_b + (size_t)l * En, h);
    kgemm8<1, 1, 0><<<dim3(8, 32), 512, 0, stream>>>(
        h, w1T + (size_t)l * En * FFn, b1 + (size_t)l * FFn, nullptr, ffn1, FFn, En);
    kgemm<128, 128, 512, 1, 1, 1, 0, 1><<<dim3(4, 64), 512, 0, stream>>>(
        ffn1, w2T + (size_t)l * FFn * En, b2 + (size_t)l * En, nullptr, x, En, FFn);
  }
  kln<<<Mn / 4, 256, 0, stream>>>(x, lnf_g, lnf_b, h);
  kgemm8<1, 0, 2><<<dim3(8, 32), 512, 0, stream>>>(
      h, wlmT, blm, outf, nullptr, Vn, En);
}